// Round 6
// baseline (389.768 us; speedup 1.0000x reference)
//
#include <hip/hip_runtime.h>
#include <hip/hip_bf16.h>
#include <math.h>

typedef __attribute__((ext_vector_type(8))) short bf16x8;
typedef __attribute__((ext_vector_type(4))) unsigned short u16x4;
typedef __attribute__((ext_vector_type(4))) float f32x4;

#define MFMA16(a, b, c) __builtin_amdgcn_mfma_f32_16x16x32_bf16(a, b, c, 0, 0, 0)

__device__ inline unsigned short f2bf(float x) {
  union { float f; unsigned u; } v; v.f = x;
  unsigned r = v.u + 0x7FFFu + ((v.u >> 16) & 1u);
  return (unsigned short)(r >> 16);
}

__device__ inline float exp2a(float x) {
  float r;
  asm("v_exp_f32 %0, %1" : "=v"(r) : "v"(x));
  return r;
}

__device__ inline void dma16(const unsigned short* g, unsigned short* l) {
  __builtin_amdgcn_global_load_lds(
      (const __attribute__((address_space(1))) unsigned int*)g,
      (__attribute__((address_space(3))) unsigned int*)l, 16, 0, 0);
}

// Fused q + kv projection. Blocks [0,2048): Q path; [2048,4096): KV path.
// W staged directly from fp32 (conv_w kernel eliminated; W is L3-resident).
// KV path nt=1 writes V^T through an LDS transpose tile (reusing w_s) so
// global stores are 64B-contiguous per thread instead of 8B @ 4KB stride.
__global__ __launch_bounds__(256) void proj_qkv(
    const float* __restrict__ Aq, const float* __restrict__ Akv,
    const float* __restrict__ Wq, const float* __restrict__ Wkv,
    unsigned short* __restrict__ outQ, unsigned short* __restrict__ outK,
    unsigned short* __restrict__ outVT, float scale)
{
  __shared__ unsigned short a_s[64 * 136];
  __shared__ unsigned short w_s[128 * 136];

  const int tid = threadIdx.x;
  const int wave = tid >> 6, lane = tid & 63, quad = lane >> 4, lr = lane & 15;
  f32x4 zero = {0.f, 0.f, 0.f, 0.f};

  if (blockIdx.x < 2048) {
    // ---------------- Q path ----------------
    const int mbase = blockIdx.x * 64;
    for (int p = 0; p < 8; ++p) {
      int r = p * 8 + (tid >> 5);
      int c = tid & 31;
      float4 v = ((const float4*)(Aq + (size_t)(mbase + r) * 128))[c];
      u16x4 pk;
      pk.x = f2bf(v.x); pk.y = f2bf(v.y); pk.z = f2bf(v.z); pk.w = f2bf(v.w);
      *(u16x4*)&a_s[r * 136 + c * 4] = pk;
    }
    for (int p = 0; p < 16; ++p) {
      int r = p * 8 + (tid >> 5);
      int c = tid & 31;
      float4 v = ((const float4*)(Wq + (size_t)r * 128))[c];
      u16x4 pk;
      pk.x = f2bf(v.x); pk.y = f2bf(v.y); pk.z = f2bf(v.z); pk.w = f2bf(v.w);
      *(u16x4*)&w_s[r * 136 + c * 4] = pk;
    }
    __syncthreads();

    f32x4 acc[8];
    for (int nb = 0; nb < 8; ++nb) acc[nb] = zero;
    for (int ks = 0; ks < 4; ++ks) {
      bf16x8 af = *(const bf16x8*)&a_s[(wave * 16 + lr) * 136 + ks * 32 + quad * 8];
      for (int nb = 0; nb < 8; ++nb) {
        bf16x8 bf = *(const bf16x8*)&w_s[(nb * 16 + lr) * 136 + ks * 32 + quad * 8];
        acc[nb] = MFMA16(af, bf, acc[nb]);
      }
    }
    for (int nb = 0; nb < 8; ++nb)
      for (int r = 0; r < 4; ++r) {
        int row = mbase + wave * 16 + quad * 4 + r;
        int col = nb * 16 + lr;
        outQ[(size_t)row * 128 + col] = f2bf(acc[nb][r] * scale);
      }
  } else {
    // ---------------- KV path ----------------
    const int mbase = (blockIdx.x - 2048) * 64;
    for (int p = 0; p < 8; ++p) {
      int r = p * 8 + (tid >> 5);
      int c = tid & 31;
      float4 v = ((const float4*)(Akv + (size_t)(mbase + r) * 128))[c];
      u16x4 pk;
      pk.x = f2bf(v.x); pk.y = f2bf(v.y); pk.z = f2bf(v.z); pk.w = f2bf(v.w);
      *(u16x4*)&a_s[r * 136 + c * 4] = pk;
    }

    for (int nt = 0; nt < 2; ++nt) {
      __syncthreads();   // nt=0: a_s staged; nt=1: all w_s/a_s reads of nt=0 done
      {
        const float* Wb = Wkv + nt * 16384;
        for (int p = 0; p < 16; ++p) {
          int r = p * 8 + (tid >> 5);
          int c = tid & 31;
          float4 v = ((const float4*)(Wb + (size_t)r * 128))[c];
          u16x4 pk;
          pk.x = f2bf(v.x); pk.y = f2bf(v.y); pk.z = f2bf(v.z); pk.w = f2bf(v.w);
          *(u16x4*)&w_s[r * 136 + c * 4] = pk;
        }
      }
      __syncthreads();

      f32x4 acc[8];
      for (int nb = 0; nb < 8; ++nb) acc[nb] = zero;
      for (int ks = 0; ks < 4; ++ks) {
        bf16x8 af = *(const bf16x8*)&a_s[(wave * 16 + lr) * 136 + ks * 32 + quad * 8];
        for (int nb = 0; nb < 8; ++nb) {
          bf16x8 bf = *(const bf16x8*)&w_s[(nb * 16 + lr) * 136 + ks * 32 + quad * 8];
          acc[nb] = MFMA16(af, bf, acc[nb]);
        }
      }

      if (nt == 0) {
        for (int nb = 0; nb < 8; ++nb)
          for (int r = 0; r < 4; ++r) {
            int row = mbase + wave * 16 + quad * 4 + r;
            int col = nb * 16 + lr;
            outK[(size_t)row * 128 + col] = f2bf(acc[nb][r]);
          }
      } else {
        // V^T via LDS transpose tile (t_s aliases w_s -- dead after MFMA).
        // t_s[col][j] stride 72: 144B rows -> 16B-aligned b128 reads.
        unsigned short* t_s = w_s;
        __syncthreads();   // all waves done reading w_s/a_s
        const int jloc = wave * 16 + quad * 4;
        for (int nb = 0; nb < 8; ++nb) {
          u16x4 pk;
          pk.x = f2bf(acc[nb][0]); pk.y = f2bf(acc[nb][1]);
          pk.z = f2bf(acc[nb][2]); pk.w = f2bf(acc[nb][3]);
          *(u16x4*)&t_s[(nb * 16 + lr) * 72 + jloc] = pk;
        }
        __syncthreads();
        // coalesced store: thread -> 64B of contiguous j for one column
        const int col = tid >> 1, hf = (tid & 1) * 32;
        unsigned short* vt = outVT + (size_t)(mbase >> 11) * 128 * 2048
                             + (size_t)col * 2048 + (mbase & 2047) + hf;
        const unsigned short* ts = &t_s[col * 72 + hf];
        for (int k2 = 0; k2 < 4; ++k2)
          *(bf16x8*)(vt + k2 * 8) = *(const bf16x8*)(ts + k2 * 8);
      }
    }
  }
}

// Flash attention, S^T formulation. v5 (FROZEN from round 5): Q-tile 256 with
// 512 threads (8 waves x 32 rows); o_acc 64 + qf 32 regs -> no spill (VGPR
// 104, WRITE collapsed to AO-only). 8 qt-blocks per bh share an XCD -> K/V
// passes L2-absorbed (FETCH 49MB). Double-buffered K/V, counted vmcnt,
// XOR-swizzled LDS.
__global__ __launch_bounds__(512, 2) void attn_fused(
    const unsigned short* __restrict__ qp,
    const unsigned short* __restrict__ kb,
    const unsigned short* __restrict__ vTb,
    unsigned short* __restrict__ ao)
{
  const int xcd = blockIdx.x & 7;
  const int loc = blockIdx.x >> 3;        // 0..63
  const int qt  = loc & 7;                // 8 Q-tiles of 256 per bh
  const int bh  = (loc >> 3) * 8 + xcd;   // 8 qt-blocks of a bh share an XCD
  const unsigned short* Q  = qp  + (size_t)bh * 2048 * 128 + (size_t)qt * 256 * 128;
  const unsigned short* K  = kb  + (size_t)bh * 2048 * 128;
  const unsigned short* VT = vTb + (size_t)bh * 128 * 2048;
  unsigned short* AO = ao + (size_t)bh * 2048 * 128 + (size_t)qt * 256 * 128;

  __shared__ unsigned short k_s [2][64 * 128];   // [j][d], 16B chunk c at c^(j&15)
  __shared__ unsigned short vT_s[2][128 * 64];   // [d][j], 16B chunk c at c^(d&7)
  __shared__ unsigned short p_s [256 * 64];      // [m][j], wave-private rows
  __shared__ float redu_s[8][2][16];             // per-wave alpha / l roundtrip

  const int tid = threadIdx.x;
  const int wave = tid >> 6, lane = tid & 63, quad = lane >> 4, lr = lane & 15;

  // per-lane DMA offsets, precomputed once (2 dma16 per wave per 16KB tile)
  const int kw_i = wave * 2;
  const int rk0  = 4 * kw_i + (lane >> 4);
  const int rk1  = 4 * (kw_i + 1) + (lane >> 4);
  const int kgo0 = rk0 * 128 + ((lane & 15) ^ (rk0 & 15)) * 8;
  const int kgo1 = rk1 * 128 + ((lane & 15) ^ (rk1 & 15)) * 8;
  const int rv0  = 8 * kw_i + (lane >> 3);
  const int rv1  = 8 * (kw_i + 1) + (lane >> 3);
  const int vsc  = ((lane & 7) ^ ((lane >> 3) & 7)) * 8;
  const int vgo0 = rv0 * 2048 + vsc;
  const int vgo1 = rv1 * 2048 + vsc;
  const int klds0 = kw_i * 512, klds1 = kw_i * 512 + 512;

#define ISSUE_K(T, BUF) do { \
    const unsigned short* _kt = K + (size_t)(T) * 8192; \
    dma16(_kt + kgo0, &k_s[BUF][klds0]); \
    dma16(_kt + kgo1, &k_s[BUF][klds1]); } while (0)
#define ISSUE_V(T, BUF) do { \
    const unsigned short* _vt = VT + (size_t)(T) * 64; \
    dma16(_vt + vgo0, &vT_s[BUF][klds0]); \
    dma16(_vt + vgo1, &vT_s[BUF][klds1]); } while (0)

  // Q fragments first (8 global loads), then DMAs -- order pinned so the
  // prologue vmcnt(2) leaves exactly K1 in flight.
  bf16x8 qf[2][4];
#pragma unroll
  for (int mb = 0; mb < 2; ++mb)
#pragma unroll
    for (int ks = 0; ks < 4; ++ks)
      qf[mb][ks] = *(const bf16x8*)(Q + (size_t)(wave * 32 + mb * 16 + lr) * 128 + ks * 32 + quad * 8);
  __builtin_amdgcn_sched_barrier(0);
  ISSUE_K(0, 0);
  ISSUE_V(0, 0);
  ISSUE_K(1, 1);
  __builtin_amdgcn_sched_barrier(0);

  f32x4 zero = {0.f, 0.f, 0.f, 0.f};
  f32x4 o_acc[2][8];
  float m_i[2], l_i[2];
#pragma unroll
  for (int mb = 0; mb < 2; ++mb) {
#pragma unroll
    for (int db = 0; db < 8; ++db) o_acc[mb][db] = zero;
    m_i[mb] = -1e30f; l_i[mb] = 0.f;
  }
  int rescM = 0;

  asm volatile("s_waitcnt vmcnt(2)" ::: "memory");  // qf,K0,V0 done; K1 in flight
  __builtin_amdgcn_s_barrier();
  __builtin_amdgcn_sched_barrier(0);
  ISSUE_V(1, 1);

#define STEP(JT, BUF) do { \
    f32x4 sT[2][4]; \
    _Pragma("unroll") \
    for (int mi = 0; mi < 2; ++mi) \
      _Pragma("unroll") \
      for (int jb = 0; jb < 4; ++jb) sT[mi][jb] = zero; \
    __builtin_amdgcn_s_setprio(1); \
    _Pragma("unroll") \
    for (int ks = 0; ks < 4; ++ks) { \
      _Pragma("unroll") \
      for (int jb = 0; jb < 4; ++jb) { \
        bf16x8 kfj = *(const bf16x8*)&k_s[BUF][(jb * 16 + lr) * 128 + (((ks * 4 + quad) ^ lr) << 3)]; \
        sT[0][jb] = MFMA16(kfj, qf[0][ks], sT[0][jb]); \
        sT[1][jb] = MFMA16(kfj, qf[1][ks], sT[1][jb]); \
      } \
    } \
    __builtin_amdgcn_s_setprio(0); \
    _Pragma("unroll") \
    for (int mi = 0; mi < 2; ++mi) { \
      const int mb = mi; \
      float mx = fmaxf(fmaxf(sT[mi][0][0], sT[mi][0][1]), fmaxf(sT[mi][0][2], sT[mi][0][3])); \
      _Pragma("unroll") \
      for (int jb = 1; jb < 4; ++jb) \
        mx = fmaxf(mx, fmaxf(fmaxf(sT[mi][jb][0], sT[mi][jb][1]), \
                             fmaxf(sT[mi][jb][2], sT[mi][jb][3]))); \
      mx = fmaxf(mx, __shfl_xor(mx, 16)); \
      mx = fmaxf(mx, __shfl_xor(mx, 32)); \
      if (!__all(mx - m_i[mb] <= 8.f)) {           /* wave-uniform */ \
        float mnew = fmaxf(m_i[mb], mx); \
        float alpha = exp2a(m_i[mb] - mnew); \
        m_i[mb] = mnew; \
        l_i[mb] *= alpha; \
        if (lane < 16) redu_s[wave][mb][lane] = alpha; \
        rescM |= (1 << (mb)); \
      } \
      float rs = 0.f; \
      const int prow = wave * 32 + mb * 16 + lr; \
      _Pragma("unroll") \
      for (int jb = 0; jb < 4; ++jb) { \
        float p0 = exp2a(sT[mi][jb][0] - m_i[mb]); \
        float p1 = exp2a(sT[mi][jb][1] - m_i[mb]); \
        float p2 = exp2a(sT[mi][jb][2] - m_i[mb]); \
        float p3 = exp2a(sT[mi][jb][3] - m_i[mb]); \
        rs += (p0 + p1) + (p2 + p3); \
        u16x4 pk; \
        pk.x = f2bf(p0); pk.y = f2bf(p1); pk.z = f2bf(p2); pk.w = f2bf(p3); \
        int c = jb * 2 + (quad >> 1); \
        *(u16x4*)&p_s[prow * 64 + ((c ^ (lr & 7)) << 3) + ((quad & 1) << 2)] = pk; \
      } \
      rs += __shfl_xor(rs, 16); \
      rs += __shfl_xor(rs, 32); \
      l_i[mb] += rs; \
    } \
    __builtin_amdgcn_s_barrier();        /* b1: all waves done with k_s[BUF] */ \
    __builtin_amdgcn_sched_barrier(0); \
    if ((JT) <= 29) ISSUE_K((JT) + 2, BUF); \
    _Pragma("unroll") \
    for (int mb = 0; mb < 2; ++mb) \
      if (rescM & (1 << (mb))) {                      /* wave-uniform */ \
        f32x4 av = *(const f32x4*)&redu_s[wave][mb][quad * 4]; \
        _Pragma("unroll") \
        for (int db = 0; db < 8; ++db) o_acc[mb][db] *= av; \
      } \
    rescM = 0; \
    __builtin_amdgcn_s_setprio(1); \
    _Pragma("unroll") \
    for (int ks2 = 0; ks2 < 2; ++ks2) { \
      const int pc = ((ks2 * 4 + quad) ^ (lr & 7)) << 3; \
      bf16x8 pf[2]; \
      _Pragma("unroll") \
      for (int mb = 0; mb < 2; ++mb) \
        pf[mb] = *(const bf16x8*)&p_s[(wave * 32 + mb * 16 + lr) * 64 + pc]; \
      _Pragma("unroll") \
      for (int db = 0; db < 8; ++db) { \
        bf16x8 vf = *(const bf16x8*)&vT_s[BUF][(db * 16 + lr) * 64 + pc]; \
        _Pragma("unroll") \
        for (int mb = 0; mb < 2; ++mb) \
          o_acc[mb][db] = MFMA16(pf[mb], vf, o_acc[mb][db]); \
      } \
    } \
    __builtin_amdgcn_s_setprio(0); \
    if ((JT) >= 30) { asm volatile("s_waitcnt vmcnt(0)" ::: "memory"); } \
    else            { asm volatile("s_waitcnt vmcnt(2)" ::: "memory"); } \
    __builtin_amdgcn_s_barrier();        /* b2: K/V(JT+1) landed; K(JT+2) in flight */ \
    __builtin_amdgcn_sched_barrier(0); \
    if ((JT) <= 29) ISSUE_V((JT) + 2, BUF); \
  } while (0)

#pragma unroll 1
  for (int jtb = 0; jtb < 16; ++jtb) {
    const int jt0 = jtb * 2;
    STEP(jt0, 0);
    STEP(jt0 + 1, 1);
  }
#undef STEP
#undef ISSUE_K
#undef ISSUE_V

  // final: l into C-layout (wave-local roundtrip), normalize, store
#pragma unroll
  for (int mb = 0; mb < 2; ++mb)
    if (lane < 16) redu_s[wave][mb][lane] = l_i[mb];
#pragma unroll
  for (int mb = 0; mb < 2; ++mb) {
    f32x4 l4 = *(const f32x4*)&redu_s[wave][mb][quad * 4];
#pragma unroll
    for (int r = 0; r < 4; ++r) {
      float inv = 1.f / l4[r];
      int row = wave * 32 + mb * 16 + quad * 4 + r;
#pragma unroll
      for (int db = 0; db < 8; ++db)
        AO[(size_t)row * 128 + db * 16 + lr] = f2bf(o_acc[mb][db][r] * inv);
    }
  }
}

// out[m,e] = sum_d AO[m,d] * Wout[e,d] + bout[e], fp32 output.
// Wout staged directly from fp32 (conv_w eliminated).
__global__ __launch_bounds__(256) void proj_out_k(
    const unsigned short* __restrict__ A, const float* __restrict__ Wout,
    const float* __restrict__ bias, float* __restrict__ out)
{
  const int mbase = blockIdx.x * 64;
  __shared__ unsigned short a_s[64 * 136];
  __shared__ unsigned short w_s[128 * 136];
  const int tid = threadIdx.x;
  {
    int r0 = tid >> 4, c = (tid & 15) * 8;
    for (int p = 0; p < 4; ++p)
      *(bf16x8*)&a_s[(p * 16 + r0) * 136 + c] =
          *(const bf16x8*)(A + (size_t)(mbase + p * 16 + r0) * 128 + c);
  }
  for (int p = 0; p < 16; ++p) {
    int r = p * 8 + (tid >> 5);
    int c = tid & 31;
    float4 v = ((const float4*)(Wout + (size_t)r * 128))[c];
    u16x4 pk;
    pk.x = f2bf(v.x); pk.y = f2bf(v.y); pk.z = f2bf(v.z); pk.w = f2bf(v.w);
    *(u16x4*)&w_s[r * 136 + c * 4] = pk;
  }
  __syncthreads();
  const int wave = tid >> 6, lane = tid & 63, quad = lane >> 4, lr = lane & 15;
  f32x4 zero = {0.f, 0.f, 0.f, 0.f};
  f32x4 acc[8];
  for (int nb = 0; nb < 8; ++nb) acc[nb] = zero;
  for (int ks = 0; ks < 4; ++ks) {
    bf16x8 af = *(const bf16x8*)&a_s[(wave * 16 + lr) * 136 + ks * 32 + quad * 8];
    for (int nb = 0; nb < 8; ++nb) {
      bf16x8 bf = *(const bf16x8*)&w_s[(nb * 16 + lr) * 136 + ks * 32 + quad * 8];
      acc[nb] = MFMA16(af, bf, acc[nb]);
    }
  }
  for (int nb = 0; nb < 8; ++nb)
    for (int r = 0; r < 4; ++r) {
      int row = mbase + wave * 16 + quad * 4 + r;
      int col = nb * 16 + lr;
      out[(size_t)row * 128 + col] = acc[nb][r] + bias[col];
    }
}

extern "C" void kernel_launch(void* const* d_in, const int* in_sizes, int n_in,
                              void* d_out, int out_size, void* d_ws, size_t ws_size,
                              hipStream_t stream) {
  const float* q    = (const float*)d_in[0];
  const float* kv   = (const float*)d_in[1];
  const float* Wq   = (const float*)d_in[2];
  const float* Wkv  = (const float*)d_in[3];
  const float* Wout = (const float*)d_in[4];
  const float* bout = (const float*)d_in[5];
  float* out = (float*)d_out;

  const size_t NELEM = (size_t)131072 * 128;
  unsigned short* qp_b = (unsigned short*)d_ws;
  unsigned short* k_b  = qp_b + NELEM;
  unsigned short* vT_b = k_b + NELEM;   // [bh][128][2048]
  unsigned short* ao_b = vT_b + NELEM;

  // 128^-0.5 * log2(e): softmax computed in exp2 domain
  const float SCALE2 = 0.08838834764831845f * 1.4426950408889634f;

  proj_qkv<<<dim3(4096), 256, 0, stream>>>(q, kv, Wq, Wkv, qp_b, k_b, vT_b, SCALE2);
  attn_fused<<<dim3(512), 512, 0, stream>>>(qp_b, k_b, vT_b, ao_b);
  proj_out_k<<<dim3(2048), 256, 0, stream>>>(ao_b, Wout, bout, out);
}

// Round 7
// 372.894 us; speedup vs baseline: 1.0453x; 1.0453x over previous
//
#include <hip/hip_runtime.h>
#include <hip/hip_bf16.h>
#include <math.h>

typedef __attribute__((ext_vector_type(8))) short bf16x8;
typedef __attribute__((ext_vector_type(4))) unsigned short u16x4;
typedef __attribute__((ext_vector_type(4))) float f32x4;

#define MFMA16(a, b, c) __builtin_amdgcn_mfma_f32_16x16x32_bf16(a, b, c, 0, 0, 0)

__device__ inline unsigned short f2bf(float x) {
  union { float f; unsigned u; } v; v.f = x;
  unsigned r = v.u + 0x7FFFu + ((v.u >> 16) & 1u);
  return (unsigned short)(r >> 16);
}

__device__ inline float exp2a(float x) {
  float r;
  asm("v_exp_f32 %0, %1" : "=v"(r) : "v"(x));
  return r;
}

__device__ inline void dma16(const unsigned short* g, unsigned short* l) {
  __builtin_amdgcn_global_load_lds(
      (const __attribute__((address_space(1))) unsigned int*)g,
      (__attribute__((address_space(3))) unsigned int*)l, 16, 0, 0);
}

// Projection weights pre-converted to bf16: [0,16K)=Wq, [16K,48K)=Wkv.
// (Wout is converted inside attn_fused's fused epilogue.)
__device__ unsigned short g_wbf[49152];

__global__ __launch_bounds__(256) void conv_w(
    const float* __restrict__ Wq, const float* __restrict__ Wkv)
{
  int idx = (blockIdx.x * 256 + threadIdx.x) * 4;   // 48 blocks -> 49152 elems
  const float* src; int off;
  if (idx < 16384) { src = Wq;  off = idx; }
  else             { src = Wkv; off = idx - 16384; }
  float4 v = *(const float4*)(src + off);
  u16x4 pk;
  pk.x = f2bf(v.x); pk.y = f2bf(v.y); pk.z = f2bf(v.z); pk.w = f2bf(v.w);
  *(u16x4*)&g_wbf[idx] = pk;
}

// q projection: C[m,n] = sum_k A[m,k]*Wq[n,k], scaled, row-major bf16 out.
__global__ __launch_bounds__(256) void proj_q(
    const float* __restrict__ A, unsigned short* __restrict__ out0, float scale)
{
  const int mbase = blockIdx.x * 64;
  const unsigned short* Wb = g_wbf;

  __shared__ unsigned short a_s[64 * 136];
  __shared__ unsigned short w_s[128 * 136];

  const int tid = threadIdx.x;
  for (int p = 0; p < 8; ++p) {
    int r = p * 8 + (tid >> 5);
    int c = tid & 31;
    float4 v = ((const float4*)(A + (size_t)(mbase + r) * 128))[c];
    u16x4 pk;
    pk.x = f2bf(v.x); pk.y = f2bf(v.y); pk.z = f2bf(v.z); pk.w = f2bf(v.w);
    *(u16x4*)&a_s[r * 136 + c * 4] = pk;
  }
  {
    int r0 = tid >> 4, c = (tid & 15) * 8;
    for (int p = 0; p < 8; ++p) {
      int r = p * 16 + r0;
      *(bf16x8*)&w_s[r * 136 + c] = *(const bf16x8*)(Wb + (size_t)r * 128 + c);
    }
  }
  __syncthreads();

  const int wave = tid >> 6, lane = tid & 63, quad = lane >> 4, lr = lane & 15;
  f32x4 zero = {0.f, 0.f, 0.f, 0.f};
  f32x4 acc[8];
  for (int nb = 0; nb < 8; ++nb) acc[nb] = zero;
  for (int ks = 0; ks < 4; ++ks) {
    bf16x8 af = *(const bf16x8*)&a_s[(wave * 16 + lr) * 136 + ks * 32 + quad * 8];
    for (int nb = 0; nb < 8; ++nb) {
      bf16x8 bf = *(const bf16x8*)&w_s[(nb * 16 + lr) * 136 + ks * 32 + quad * 8];
      acc[nb] = MFMA16(af, bf, acc[nb]);
    }
  }
  for (int nb = 0; nb < 8; ++nb)
    for (int r = 0; r < 4; ++r) {
      int row = mbase + wave * 16 + quad * 4 + r;
      int col = nb * 16 + lr;
      out0[(size_t)row * 128 + col] = f2bf(acc[nb][r] * scale);
    }
}

// kv projection, both halves from ONE A staging: nt=0 -> K row-major,
// nt=1 -> V^T [bh][128][2048].
__global__ __launch_bounds__(256) void proj_kv(
    const float* __restrict__ A,
    unsigned short* __restrict__ outK, unsigned short* __restrict__ outVT)
{
  const int mbase = blockIdx.x * 64;
  __shared__ unsigned short a_s[64 * 136];
  __shared__ unsigned short w_s[128 * 136];
  const int tid = threadIdx.x;

  for (int p = 0; p < 8; ++p) {
    int r = p * 8 + (tid >> 5);
    int c = tid & 31;
    float4 v = ((const float4*)(A + (size_t)(mbase + r) * 128))[c];
    u16x4 pk;
    pk.x = f2bf(v.x); pk.y = f2bf(v.y); pk.z = f2bf(v.z); pk.w = f2bf(v.w);
    *(u16x4*)&a_s[r * 136 + c * 4] = pk;
  }

  const int wave = tid >> 6, lane = tid & 63, quad = lane >> 4, lr = lane & 15;
  f32x4 zero = {0.f, 0.f, 0.f, 0.f};

  for (int nt = 0; nt < 2; ++nt) {
    __syncthreads();   // nt=0: A staged; nt=1: all w_s reads done
    {
      const unsigned short* Wb = g_wbf + 16384 + nt * 16384;
      int r0 = tid >> 4, c = (tid & 15) * 8;
      for (int p = 0; p < 8; ++p) {
        int r = p * 16 + r0;
        *(bf16x8*)&w_s[r * 136 + c] = *(const bf16x8*)(Wb + (size_t)r * 128 + c);
      }
    }
    __syncthreads();

    f32x4 acc[8];
    for (int nb = 0; nb < 8; ++nb) acc[nb] = zero;
    for (int ks = 0; ks < 4; ++ks) {
      bf16x8 af = *(const bf16x8*)&a_s[(wave * 16 + lr) * 136 + ks * 32 + quad * 8];
      for (int nb = 0; nb < 8; ++nb) {
        bf16x8 bf = *(const bf16x8*)&w_s[(nb * 16 + lr) * 136 + ks * 32 + quad * 8];
        acc[nb] = MFMA16(af, bf, acc[nb]);
      }
    }

    if (nt == 0) {
      for (int nb = 0; nb < 8; ++nb)
        for (int r = 0; r < 4; ++r) {
          int row = mbase + wave * 16 + quad * 4 + r;
          int col = nb * 16 + lr;
          outK[(size_t)row * 128 + col] = f2bf(acc[nb][r]);
        }
    } else {
      int gm = mbase + wave * 16 + quad * 4;
      int bh = gm >> 11;
      int j  = gm & 2047;
      unsigned short* vt = outVT + (size_t)bh * 128 * 2048;
      for (int nb = 0; nb < 8; ++nb) {
        int col = nb * 16 + lr;
        u16x4 pk;
        pk.x = f2bf(acc[nb][0]); pk.y = f2bf(acc[nb][1]);
        pk.z = f2bf(acc[nb][2]); pk.w = f2bf(acc[nb][3]);
        *(u16x4*)&vt[(size_t)col * 2048 + j] = pk;
      }
    }
  }
}

// Flash attention + FUSED OUTPUT PROJECTION. Main loop FROZEN from round 5
// (194.6us, no spill, FETCH 49MB). Epilogue: OUT = (O/l) @ Wout^T + bias
// computed in-kernel -- normalized O goes through wave-private p_s (XOR
// swizzle, 2 k-halves), Wout staged fp32->bf16 into wout_s (LDS 131KB total,
// still 1 block/CU). Eliminates proj_out_k kernel + 67MB AO HBM roundtrip.
__global__ __launch_bounds__(512, 2) void attn_fused(
    const unsigned short* __restrict__ qp,
    const unsigned short* __restrict__ kb,
    const unsigned short* __restrict__ vTb,
    const float* __restrict__ Wout,
    const float* __restrict__ bias,
    float* __restrict__ out)
{
  const int xcd = blockIdx.x & 7;
  const int loc = blockIdx.x >> 3;        // 0..63
  const int qt  = loc & 7;                // 8 Q-tiles of 256 per bh
  const int bh  = (loc >> 3) * 8 + xcd;   // 8 qt-blocks of a bh share an XCD
  const unsigned short* Q  = qp  + (size_t)bh * 2048 * 128 + (size_t)qt * 256 * 128;
  const unsigned short* K  = kb  + (size_t)bh * 2048 * 128;
  const unsigned short* VT = vTb + (size_t)bh * 128 * 2048;
  float* OUT = out + (size_t)bh * 2048 * 128 + (size_t)qt * 256 * 128;

  __shared__ unsigned short k_s [2][64 * 128];   // [j][d], 16B chunk c at c^(j&15)
  __shared__ unsigned short vT_s[2][128 * 64];   // [d][j], 16B chunk c at c^(d&7)
  __shared__ unsigned short p_s [256 * 64];      // [m][j], wave-private rows
  __shared__ float redu_s[8][2][16];             // per-wave alpha / l roundtrip
  __shared__ unsigned short wout_s[128 * 136];   // epilogue: Wout bf16

  const int tid = threadIdx.x;
  const int wave = tid >> 6, lane = tid & 63, quad = lane >> 4, lr = lane & 15;

  // per-lane DMA offsets, precomputed once (2 dma16 per wave per 16KB tile)
  const int kw_i = wave * 2;
  const int rk0  = 4 * kw_i + (lane >> 4);
  const int rk1  = 4 * (kw_i + 1) + (lane >> 4);
  const int kgo0 = rk0 * 128 + ((lane & 15) ^ (rk0 & 15)) * 8;
  const int kgo1 = rk1 * 128 + ((lane & 15) ^ (rk1 & 15)) * 8;
  const int rv0  = 8 * kw_i + (lane >> 3);
  const int rv1  = 8 * (kw_i + 1) + (lane >> 3);
  const int vsc  = ((lane & 7) ^ ((lane >> 3) & 7)) * 8;
  const int vgo0 = rv0 * 2048 + vsc;
  const int vgo1 = rv1 * 2048 + vsc;
  const int klds0 = kw_i * 512, klds1 = kw_i * 512 + 512;

#define ISSUE_K(T, BUF) do { \
    const unsigned short* _kt = K + (size_t)(T) * 8192; \
    dma16(_kt + kgo0, &k_s[BUF][klds0]); \
    dma16(_kt + kgo1, &k_s[BUF][klds1]); } while (0)
#define ISSUE_V(T, BUF) do { \
    const unsigned short* _vt = VT + (size_t)(T) * 64; \
    dma16(_vt + vgo0, &vT_s[BUF][klds0]); \
    dma16(_vt + vgo1, &vT_s[BUF][klds1]); } while (0)

  // Q fragments first (8 global loads), then DMAs -- order pinned so the
  // prologue vmcnt(2) leaves exactly K1 in flight.
  bf16x8 qf[2][4];
#pragma unroll
  for (int mb = 0; mb < 2; ++mb)
#pragma unroll
    for (int ks = 0; ks < 4; ++ks)
      qf[mb][ks] = *(const bf16x8*)(Q + (size_t)(wave * 32 + mb * 16 + lr) * 128 + ks * 32 + quad * 8);
  __builtin_amdgcn_sched_barrier(0);
  ISSUE_K(0, 0);
  ISSUE_V(0, 0);
  ISSUE_K(1, 1);
  __builtin_amdgcn_sched_barrier(0);

  f32x4 zero = {0.f, 0.f, 0.f, 0.f};
  f32x4 o_acc[2][8];
  float m_i[2], l_i[2];
#pragma unroll
  for (int mb = 0; mb < 2; ++mb) {
#pragma unroll
    for (int db = 0; db < 8; ++db) o_acc[mb][db] = zero;
    m_i[mb] = -1e30f; l_i[mb] = 0.f;
  }
  int rescM = 0;

  asm volatile("s_waitcnt vmcnt(2)" ::: "memory");  // qf,K0,V0 done; K1 in flight
  __builtin_amdgcn_s_barrier();
  __builtin_amdgcn_sched_barrier(0);
  ISSUE_V(1, 1);

#define STEP(JT, BUF) do { \
    f32x4 sT[2][4]; \
    _Pragma("unroll") \
    for (int mi = 0; mi < 2; ++mi) \
      _Pragma("unroll") \
      for (int jb = 0; jb < 4; ++jb) sT[mi][jb] = zero; \
    __builtin_amdgcn_s_setprio(1); \
    _Pragma("unroll") \
    for (int ks = 0; ks < 4; ++ks) { \
      _Pragma("unroll") \
      for (int jb = 0; jb < 4; ++jb) { \
        bf16x8 kfj = *(const bf16x8*)&k_s[BUF][(jb * 16 + lr) * 128 + (((ks * 4 + quad) ^ lr) << 3)]; \
        sT[0][jb] = MFMA16(kfj, qf[0][ks], sT[0][jb]); \
        sT[1][jb] = MFMA16(kfj, qf[1][ks], sT[1][jb]); \
      } \
    } \
    __builtin_amdgcn_s_setprio(0); \
    _Pragma("unroll") \
    for (int mi = 0; mi < 2; ++mi) { \
      const int mb = mi; \
      float mx = fmaxf(fmaxf(sT[mi][0][0], sT[mi][0][1]), fmaxf(sT[mi][0][2], sT[mi][0][3])); \
      _Pragma("unroll") \
      for (int jb = 1; jb < 4; ++jb) \
        mx = fmaxf(mx, fmaxf(fmaxf(sT[mi][jb][0], sT[mi][jb][1]), \
                             fmaxf(sT[mi][jb][2], sT[mi][jb][3]))); \
      mx = fmaxf(mx, __shfl_xor(mx, 16)); \
      mx = fmaxf(mx, __shfl_xor(mx, 32)); \
      if (!__all(mx - m_i[mb] <= 8.f)) {           /* wave-uniform */ \
        float mnew = fmaxf(m_i[mb], mx); \
        float alpha = exp2a(m_i[mb] - mnew); \
        m_i[mb] = mnew; \
        l_i[mb] *= alpha; \
        if (lane < 16) redu_s[wave][mb][lane] = alpha; \
        rescM |= (1 << (mb)); \
      } \
      float rs = 0.f; \
      const int prow = wave * 32 + mb * 16 + lr; \
      _Pragma("unroll") \
      for (int jb = 0; jb < 4; ++jb) { \
        float p0 = exp2a(sT[mi][jb][0] - m_i[mb]); \
        float p1 = exp2a(sT[mi][jb][1] - m_i[mb]); \
        float p2 = exp2a(sT[mi][jb][2] - m_i[mb]); \
        float p3 = exp2a(sT[mi][jb][3] - m_i[mb]); \
        rs += (p0 + p1) + (p2 + p3); \
        u16x4 pk; \
        pk.x = f2bf(p0); pk.y = f2bf(p1); pk.z = f2bf(p2); pk.w = f2bf(p3); \
        int c = jb * 2 + (quad >> 1); \
        *(u16x4*)&p_s[prow * 64 + ((c ^ (lr & 7)) << 3) + ((quad & 1) << 2)] = pk; \
      } \
      rs += __shfl_xor(rs, 16); \
      rs += __shfl_xor(rs, 32); \
      l_i[mb] += rs; \
    } \
    __builtin_amdgcn_s_barrier();        /* b1: all waves done with k_s[BUF] */ \
    __builtin_amdgcn_sched_barrier(0); \
    if ((JT) <= 29) ISSUE_K((JT) + 2, BUF); \
    _Pragma("unroll") \
    for (int mb = 0; mb < 2; ++mb) \
      if (rescM & (1 << (mb))) {                      /* wave-uniform */ \
        f32x4 av = *(const f32x4*)&redu_s[wave][mb][quad * 4]; \
        _Pragma("unroll") \
        for (int db = 0; db < 8; ++db) o_acc[mb][db] *= av; \
      } \
    rescM = 0; \
    __builtin_amdgcn_s_setprio(1); \
    _Pragma("unroll") \
    for (int ks2 = 0; ks2 < 2; ++ks2) { \
      const int pc = ((ks2 * 4 + quad) ^ (lr & 7)) << 3; \
      bf16x8 pf[2]; \
      _Pragma("unroll") \
      for (int mb = 0; mb < 2; ++mb) \
        pf[mb] = *(const bf16x8*)&p_s[(wave * 32 + mb * 16 + lr) * 64 + pc]; \
      _Pragma("unroll") \
      for (int db = 0; db < 8; ++db) { \
        bf16x8 vf = *(const bf16x8*)&vT_s[BUF][(db * 16 + lr) * 64 + pc]; \
        _Pragma("unroll") \
        for (int mb = 0; mb < 2; ++mb) \
          o_acc[mb][db] = MFMA16(pf[mb], vf, o_acc[mb][db]); \
      } \
    } \
    __builtin_amdgcn_s_setprio(0); \
    if ((JT) >= 30) { asm volatile("s_waitcnt vmcnt(0)" ::: "memory"); } \
    else            { asm volatile("s_waitcnt vmcnt(2)" ::: "memory"); } \
    __builtin_amdgcn_s_barrier();        /* b2: K/V(JT+1) landed; K(JT+2) in flight */ \
    __builtin_amdgcn_sched_barrier(0); \
    if ((JT) <= 29) ISSUE_V((JT) + 2, BUF); \
  } while (0)

#pragma unroll 1
  for (int jtb = 0; jtb < 16; ++jtb) {
    const int jt0 = jtb * 2;
    STEP(jt0, 0);
    STEP(jt0 + 1, 1);
  }
#undef STEP
#undef ISSUE_K
#undef ISSUE_V

  // ================= fused output projection epilogue =================
  // stage Wout fp32 -> bf16 into wout_s (512 threads cover 128x128)
#pragma unroll
  for (int p = 0; p < 4; ++p) {
    int r = p * 32 + (tid >> 4);
    int c = (tid & 15) * 8;
    float4 v0 = *(const float4*)(Wout + (size_t)r * 128 + c);
    float4 v1 = *(const float4*)(Wout + (size_t)r * 128 + c + 4);
    u16x4 pk0, pk1;
    pk0.x = f2bf(v0.x); pk0.y = f2bf(v0.y); pk0.z = f2bf(v0.z); pk0.w = f2bf(v0.w);
    pk1.x = f2bf(v1.x); pk1.y = f2bf(v1.y); pk1.z = f2bf(v1.z); pk1.w = f2bf(v1.w);
    *(u16x4*)&wout_s[r * 136 + c] = pk0;
    *(u16x4*)&wout_s[r * 136 + c + 4] = pk1;
  }

  // l into C-layout (wave-local roundtrip), fold 1/l into o_acc
#pragma unroll
  for (int mb = 0; mb < 2; ++mb)
    if (lane < 16) redu_s[wave][mb][lane] = l_i[mb];
#pragma unroll
  for (int mb = 0; mb < 2; ++mb) {
    f32x4 l4 = *(const f32x4*)&redu_s[wave][mb][quad * 4];
    f32x4 invv;
#pragma unroll
    for (int r = 0; r < 4; ++r) invv[r] = 1.f / l4[r];
#pragma unroll
    for (int db = 0; db < 8; ++db) o_acc[mb][db] *= invv;
  }

  __syncthreads();   // wout_s staged (also: all waves past main loop)

  f32x4 acc2[2][8];
#pragma unroll
  for (int mb = 0; mb < 2; ++mb)
#pragma unroll
    for (int nb = 0; nb < 8; ++nb) acc2[mb][nb] = zero;

  // two k-halves through the wave-private p_s region (rows wave*32..+32)
#pragma unroll
  for (int h = 0; h < 2; ++h) {
    // write normalized O[:, h*64 .. h*64+64) as bf16 into p_s, XOR-swizzled
#pragma unroll
    for (int mb = 0; mb < 2; ++mb)
#pragma unroll
      for (int db2 = 0; db2 < 4; ++db2) {
        f32x4 o = o_acc[mb][h * 4 + db2];
#pragma unroll
        for (int r = 0; r < 4; ++r) {
          int row = mb * 16 + quad * 4 + r;     // within wave's 32 rows
          int colh = db2 * 16 + lr;             // 0..63 within half
          int chunk = colh >> 3, off = colh & 7;
          p_s[(wave * 32 + row) * 64 + ((chunk ^ (row & 7)) << 3) + off] = f2bf(o[r]);
        }
      }
    // wave-private: compiler inserts lgkmcnt before dependent reads
#pragma unroll
    for (int ks = 0; ks < 2; ++ks) {
#pragma unroll
      for (int mb = 0; mb < 2; ++mb) {
        int arow = mb * 16 + lr;
        int kk = ks * 32 + quad * 8;            // 0..63 within half
        int chunk = kk >> 3;                    // 16B-aligned
        bf16x8 af = *(const bf16x8*)&p_s[(wave * 32 + arow) * 64 + ((chunk ^ (arow & 7)) << 3)];
#pragma unroll
        for (int nb = 0; nb < 8; ++nb) {
          bf16x8 bf = *(const bf16x8*)&wout_s[(nb * 16 + lr) * 136 + h * 64 + kk];
          acc2[mb][nb] = MFMA16(af, bf, acc2[mb][nb]);
        }
      }
    }
  }

  // store fp32 output + bias
#pragma unroll
  for (int mb = 0; mb < 2; ++mb)
#pragma unroll
    for (int nb = 0; nb < 8; ++nb) {
      int col = nb * 16 + lr;
      float b = bias[col];
#pragma unroll
      for (int r = 0; r < 4; ++r) {
        int row = wave * 32 + mb * 16 + quad * 4 + r;
        OUT[(size_t)row * 128 + col] = acc2[mb][nb][r] + b;
      }
    }
}

extern "C" void kernel_launch(void* const* d_in, const int* in_sizes, int n_in,
                              void* d_out, int out_size, void* d_ws, size_t ws_size,
                              hipStream_t stream) {
  const float* q    = (const float*)d_in[0];
  const float* kv   = (const float*)d_in[1];
  const float* Wq   = (const float*)d_in[2];
  const float* Wkv  = (const float*)d_in[3];
  const float* Wout = (const float*)d_in[4];
  const float* bout = (const float*)d_in[5];
  float* out = (float*)d_out;

  const size_t NELEM = (size_t)131072 * 128;
  unsigned short* qp_b = (unsigned short*)d_ws;
  unsigned short* k_b  = qp_b + NELEM;
  unsigned short* vT_b = k_b + NELEM;   // [bh][128][2048]

  // 128^-0.5 * log2(e): softmax computed in exp2 domain
  const float SCALE2 = 0.08838834764831845f * 1.4426950408889634f;

  conv_w<<<dim3(48), 256, 0, stream>>>(Wq, Wkv);
  proj_q<<<dim3(2048), 256, 0, stream>>>(q, qp_b, SCALE2);
  proj_kv<<<dim3(2048), 256, 0, stream>>>(kv, k_b, vT_b);
  attn_fused<<<dim3(512), 512, 0, stream>>>(qp_b, k_b, vT_b, Wout, bout, out);
}

// Round 8
// 362.590 us; speedup vs baseline: 1.0750x; 1.0284x over previous
//
#include <hip/hip_runtime.h>
#include <hip/hip_bf16.h>
#include <math.h>

typedef __attribute__((ext_vector_type(8))) short bf16x8;
typedef __attribute__((ext_vector_type(4))) unsigned short u16x4;
typedef __attribute__((ext_vector_type(4))) float f32x4;

#define MFMA16(a, b, c) __builtin_amdgcn_mfma_f32_16x16x32_bf16(a, b, c, 0, 0, 0)

__device__ inline unsigned short f2bf(float x) {
  union { float f; unsigned u; } v; v.f = x;
  unsigned r = v.u + 0x7FFFu + ((v.u >> 16) & 1u);
  return (unsigned short)(r >> 16);
}

__device__ inline float exp2a(float x) {
  float r;
  asm("v_exp_f32 %0, %1" : "=v"(r) : "v"(x));
  return r;
}

__device__ inline void dma16(const unsigned short* g, unsigned short* l) {
  __builtin_amdgcn_global_load_lds(
      (const __attribute__((address_space(1))) unsigned int*)g,
      (__attribute__((address_space(3))) unsigned int*)l, 16, 0, 0);
}

// Projection weights pre-converted to bf16: [0,16K)=Wq, [16K,48K)=Wkv.
// (Wout is converted inside attn_fused's fused epilogue.)
__device__ unsigned short g_wbf[49152];

__global__ __launch_bounds__(256) void conv_w(
    const float* __restrict__ Wq, const float* __restrict__ Wkv)
{
  int idx = (blockIdx.x * 256 + threadIdx.x) * 4;   // 48 blocks -> 49152 elems
  const float* src; int off;
  if (idx < 16384) { src = Wq;  off = idx; }
  else             { src = Wkv; off = idx - 16384; }
  float4 v = *(const float4*)(src + off);
  u16x4 pk;
  pk.x = f2bf(v.x); pk.y = f2bf(v.y); pk.z = f2bf(v.z); pk.w = f2bf(v.w);
  *(u16x4*)&g_wbf[idx] = pk;
}

// Merged q + kv projection (one launch, 4096 blocks; the two GEMMs overlap
// across CUs and one launch gap disappears). W staged bf16 from g_wbf (the
// r5-proven path -- NOT per-block fp32 conversion, which regressed in r6).
// Blocks [0,2048): Q path. [2048,4096): KV path; nt=1 writes V^T through an
// LDS transpose tile so global stores are 64B-contiguous per thread instead
// of 8B @ 4KB stride (clean single-variable retest of r6's fix).
__global__ __launch_bounds__(256) void proj_qkv(
    const float* __restrict__ Aq, const float* __restrict__ Akv,
    unsigned short* __restrict__ outQ, unsigned short* __restrict__ outK,
    unsigned short* __restrict__ outVT, float scale)
{
  __shared__ unsigned short a_s[64 * 136];
  __shared__ unsigned short w_s[128 * 136];

  const int tid = threadIdx.x;
  const int wave = tid >> 6, lane = tid & 63, quad = lane >> 4, lr = lane & 15;
  f32x4 zero = {0.f, 0.f, 0.f, 0.f};

  if (blockIdx.x < 2048) {
    // ---------------- Q path ----------------
    const int mbase = blockIdx.x * 64;
    for (int p = 0; p < 8; ++p) {
      int r = p * 8 + (tid >> 5);
      int c = tid & 31;
      float4 v = ((const float4*)(Aq + (size_t)(mbase + r) * 128))[c];
      u16x4 pk;
      pk.x = f2bf(v.x); pk.y = f2bf(v.y); pk.z = f2bf(v.z); pk.w = f2bf(v.w);
      *(u16x4*)&a_s[r * 136 + c * 4] = pk;
    }
    {
      const unsigned short* Wb = g_wbf;
      int r0 = tid >> 4, c = (tid & 15) * 8;
      for (int p = 0; p < 8; ++p) {
        int r = p * 16 + r0;
        *(bf16x8*)&w_s[r * 136 + c] = *(const bf16x8*)(Wb + (size_t)r * 128 + c);
      }
    }
    __syncthreads();

    f32x4 acc[8];
    for (int nb = 0; nb < 8; ++nb) acc[nb] = zero;
    for (int ks = 0; ks < 4; ++ks) {
      bf16x8 af = *(const bf16x8*)&a_s[(wave * 16 + lr) * 136 + ks * 32 + quad * 8];
      for (int nb = 0; nb < 8; ++nb) {
        bf16x8 bf = *(const bf16x8*)&w_s[(nb * 16 + lr) * 136 + ks * 32 + quad * 8];
        acc[nb] = MFMA16(af, bf, acc[nb]);
      }
    }
    for (int nb = 0; nb < 8; ++nb)
      for (int r = 0; r < 4; ++r) {
        int row = mbase + wave * 16 + quad * 4 + r;
        int col = nb * 16 + lr;
        outQ[(size_t)row * 128 + col] = f2bf(acc[nb][r] * scale);
      }
  } else {
    // ---------------- KV path ----------------
    const int mbase = (blockIdx.x - 2048) * 64;
    for (int p = 0; p < 8; ++p) {
      int r = p * 8 + (tid >> 5);
      int c = tid & 31;
      float4 v = ((const float4*)(Akv + (size_t)(mbase + r) * 128))[c];
      u16x4 pk;
      pk.x = f2bf(v.x); pk.y = f2bf(v.y); pk.z = f2bf(v.z); pk.w = f2bf(v.w);
      *(u16x4*)&a_s[r * 136 + c * 4] = pk;
    }

    for (int nt = 0; nt < 2; ++nt) {
      __syncthreads();   // nt=0: a_s staged; nt=1: all w_s reads done
      {
        const unsigned short* Wb = g_wbf + 16384 + nt * 16384;
        int r0 = tid >> 4, c = (tid & 15) * 8;
        for (int p = 0; p < 8; ++p) {
          int r = p * 16 + r0;
          *(bf16x8*)&w_s[r * 136 + c] = *(const bf16x8*)(Wb + (size_t)r * 128 + c);
        }
      }
      __syncthreads();

      f32x4 acc[8];
      for (int nb = 0; nb < 8; ++nb) acc[nb] = zero;
      for (int ks = 0; ks < 4; ++ks) {
        bf16x8 af = *(const bf16x8*)&a_s[(wave * 16 + lr) * 136 + ks * 32 + quad * 8];
        for (int nb = 0; nb < 8; ++nb) {
          bf16x8 bf = *(const bf16x8*)&w_s[(nb * 16 + lr) * 136 + ks * 32 + quad * 8];
          acc[nb] = MFMA16(af, bf, acc[nb]);
        }
      }

      if (nt == 0) {
        for (int nb = 0; nb < 8; ++nb)
          for (int r = 0; r < 4; ++r) {
            int row = mbase + wave * 16 + quad * 4 + r;
            int col = nb * 16 + lr;
            outK[(size_t)row * 128 + col] = f2bf(acc[nb][r]);
          }
      } else {
        // V^T via LDS transpose tile (t_s aliases w_s -- dead after MFMA).
        // t_s[col][j] stride 72: 8B-aligned writes, conflict-free b128 reads.
        unsigned short* t_s = w_s;
        __syncthreads();   // all waves done reading w_s/a_s
        const int jloc = wave * 16 + quad * 4;
        for (int nb = 0; nb < 8; ++nb) {
          u16x4 pk;
          pk.x = f2bf(acc[nb][0]); pk.y = f2bf(acc[nb][1]);
          pk.z = f2bf(acc[nb][2]); pk.w = f2bf(acc[nb][3]);
          *(u16x4*)&t_s[(nb * 16 + lr) * 72 + jloc] = pk;
        }
        __syncthreads();
        // coalesced store: thread -> 64B of contiguous j for one column
        const int col = tid >> 1, hf = (tid & 1) * 32;
        unsigned short* vt = outVT + (size_t)(mbase >> 11) * 128 * 2048
                             + (size_t)col * 2048 + (mbase & 2047) + hf;
        const unsigned short* ts = &t_s[col * 72 + hf];
        for (int k2 = 0; k2 < 4; ++k2)
          *(bf16x8*)(vt + k2 * 8) = *(const bf16x8*)(ts + k2 * 8);
      }
    }
  }
}

// Flash attention + FUSED OUTPUT PROJECTION. Main loop FROZEN from round 5
// (no spill, FETCH 49MB). Epilogue: OUT = (O/l) @ Wout^T + bias in-kernel --
// normalized O goes through wave-private p_s (XOR swizzle, 2 k-halves), Wout
// staged fp32->bf16 into wout_s (LDS 131KB, 1 block/CU). 206.6us @ r7.
__global__ __launch_bounds__(512, 2) void attn_fused(
    const unsigned short* __restrict__ qp,
    const unsigned short* __restrict__ kb,
    const unsigned short* __restrict__ vTb,
    const float* __restrict__ Wout,
    const float* __restrict__ bias,
    float* __restrict__ out)
{
  const int xcd = blockIdx.x & 7;
  const int loc = blockIdx.x >> 3;        // 0..63
  const int qt  = loc & 7;                // 8 Q-tiles of 256 per bh
  const int bh  = (loc >> 3) * 8 + xcd;   // 8 qt-blocks of a bh share an XCD
  const unsigned short* Q  = qp  + (size_t)bh * 2048 * 128 + (size_t)qt * 256 * 128;
  const unsigned short* K  = kb  + (size_t)bh * 2048 * 128;
  const unsigned short* VT = vTb + (size_t)bh * 128 * 2048;
  float* OUT = out + (size_t)bh * 2048 * 128 + (size_t)qt * 256 * 128;

  __shared__ unsigned short k_s [2][64 * 128];   // [j][d], 16B chunk c at c^(j&15)
  __shared__ unsigned short vT_s[2][128 * 64];   // [d][j], 16B chunk c at c^(d&7)
  __shared__ unsigned short p_s [256 * 64];      // [m][j], wave-private rows
  __shared__ float redu_s[8][2][16];             // per-wave alpha / l roundtrip
  __shared__ unsigned short wout_s[128 * 136];   // epilogue: Wout bf16

  const int tid = threadIdx.x;
  const int wave = tid >> 6, lane = tid & 63, quad = lane >> 4, lr = lane & 15;

  // per-lane DMA offsets, precomputed once (2 dma16 per wave per 16KB tile)
  const int kw_i = wave * 2;
  const int rk0  = 4 * kw_i + (lane >> 4);
  const int rk1  = 4 * (kw_i + 1) + (lane >> 4);
  const int kgo0 = rk0 * 128 + ((lane & 15) ^ (rk0 & 15)) * 8;
  const int kgo1 = rk1 * 128 + ((lane & 15) ^ (rk1 & 15)) * 8;
  const int rv0  = 8 * kw_i + (lane >> 3);
  const int rv1  = 8 * (kw_i + 1) + (lane >> 3);
  const int vsc  = ((lane & 7) ^ ((lane >> 3) & 7)) * 8;
  const int vgo0 = rv0 * 2048 + vsc;
  const int vgo1 = rv1 * 2048 + vsc;
  const int klds0 = kw_i * 512, klds1 = kw_i * 512 + 512;

#define ISSUE_K(T, BUF) do { \
    const unsigned short* _kt = K + (size_t)(T) * 8192; \
    dma16(_kt + kgo0, &k_s[BUF][klds0]); \
    dma16(_kt + kgo1, &k_s[BUF][klds1]); } while (0)
#define ISSUE_V(T, BUF) do { \
    const unsigned short* _vt = VT + (size_t)(T) * 64; \
    dma16(_vt + vgo0, &vT_s[BUF][klds0]); \
    dma16(_vt + vgo1, &vT_s[BUF][klds1]); } while (0)

  // Q fragments first (8 global loads), then DMAs -- order pinned so the
  // prologue vmcnt(2) leaves exactly K1 in flight.
  bf16x8 qf[2][4];
#pragma unroll
  for (int mb = 0; mb < 2; ++mb)
#pragma unroll
    for (int ks = 0; ks < 4; ++ks)
      qf[mb][ks] = *(const bf16x8*)(Q + (size_t)(wave * 32 + mb * 16 + lr) * 128 + ks * 32 + quad * 8);
  __builtin_amdgcn_sched_barrier(0);
  ISSUE_K(0, 0);
  ISSUE_V(0, 0);
  ISSUE_K(1, 1);
  __builtin_amdgcn_sched_barrier(0);

  f32x4 zero = {0.f, 0.f, 0.f, 0.f};
  f32x4 o_acc[2][8];
  float m_i[2], l_i[2];
#pragma unroll
  for (int mb = 0; mb < 2; ++mb) {
#pragma unroll
    for (int db = 0; db < 8; ++db) o_acc[mb][db] = zero;
    m_i[mb] = -1e30f; l_i[mb] = 0.f;
  }
  int rescM = 0;

  asm volatile("s_waitcnt vmcnt(2)" ::: "memory");  // qf,K0,V0 done; K1 in flight
  __builtin_amdgcn_s_barrier();
  __builtin_amdgcn_sched_barrier(0);
  ISSUE_V(1, 1);

#define STEP(JT, BUF) do { \
    f32x4 sT[2][4]; \
    _Pragma("unroll") \
    for (int mi = 0; mi < 2; ++mi) \
      _Pragma("unroll") \
      for (int jb = 0; jb < 4; ++jb) sT[mi][jb] = zero; \
    __builtin_amdgcn_s_setprio(1); \
    _Pragma("unroll") \
    for (int ks = 0; ks < 4; ++ks) { \
      _Pragma("unroll") \
      for (int jb = 0; jb < 4; ++jb) { \
        bf16x8 kfj = *(const bf16x8*)&k_s[BUF][(jb * 16 + lr) * 128 + (((ks * 4 + quad) ^ lr) << 3)]; \
        sT[0][jb] = MFMA16(kfj, qf[0][ks], sT[0][jb]); \
        sT[1][jb] = MFMA16(kfj, qf[1][ks], sT[1][jb]); \
      } \
    } \
    __builtin_amdgcn_s_setprio(0); \
    _Pragma("unroll") \
    for (int mi = 0; mi < 2; ++mi) { \
      const int mb = mi; \
      float mx = fmaxf(fmaxf(sT[mi][0][0], sT[mi][0][1]), fmaxf(sT[mi][0][2], sT[mi][0][3])); \
      _Pragma("unroll") \
      for (int jb = 1; jb < 4; ++jb) \
        mx = fmaxf(mx, fmaxf(fmaxf(sT[mi][jb][0], sT[mi][jb][1]), \
                             fmaxf(sT[mi][jb][2], sT[mi][jb][3]))); \
      mx = fmaxf(mx, __shfl_xor(mx, 16)); \
      mx = fmaxf(mx, __shfl_xor(mx, 32)); \
      if (!__all(mx - m_i[mb] <= 8.f)) {           /* wave-uniform */ \
        float mnew = fmaxf(m_i[mb], mx); \
        float alpha = exp2a(m_i[mb] - mnew); \
        m_i[mb] = mnew; \
        l_i[mb] *= alpha; \
        if (lane < 16) redu_s[wave][mb][lane] = alpha; \
        rescM |= (1 << (mb)); \
      } \
      float rs = 0.f; \
      const int prow = wave * 32 + mb * 16 + lr; \
      _Pragma("unroll") \
      for (int jb = 0; jb < 4; ++jb) { \
        float p0 = exp2a(sT[mi][jb][0] - m_i[mb]); \
        float p1 = exp2a(sT[mi][jb][1] - m_i[mb]); \
        float p2 = exp2a(sT[mi][jb][2] - m_i[mb]); \
        float p3 = exp2a(sT[mi][jb][3] - m_i[mb]); \
        rs += (p0 + p1) + (p2 + p3); \
        u16x4 pk; \
        pk.x = f2bf(p0); pk.y = f2bf(p1); pk.z = f2bf(p2); pk.w = f2bf(p3); \
        int c = jb * 2 + (quad >> 1); \
        *(u16x4*)&p_s[prow * 64 + ((c ^ (lr & 7)) << 3) + ((quad & 1) << 2)] = pk; \
      } \
      rs += __shfl_xor(rs, 16); \
      rs += __shfl_xor(rs, 32); \
      l_i[mb] += rs; \
    } \
    __builtin_amdgcn_s_barrier();        /* b1: all waves done with k_s[BUF] */ \
    __builtin_amdgcn_sched_barrier(0); \
    if ((JT) <= 29) ISSUE_K((JT) + 2, BUF); \
    _Pragma("unroll") \
    for (int mb = 0; mb < 2; ++mb) \
      if (rescM & (1 << (mb))) {                      /* wave-uniform */ \
        f32x4 av = *(const f32x4*)&redu_s[wave][mb][quad * 4]; \
        _Pragma("unroll") \
        for (int db = 0; db < 8; ++db) o_acc[mb][db] *= av; \
      } \
    rescM = 0; \
    __builtin_amdgcn_s_setprio(1); \
    _Pragma("unroll") \
    for (int ks2 = 0; ks2 < 2; ++ks2) { \
      const int pc = ((ks2 * 4 + quad) ^ (lr & 7)) << 3; \
      bf16x8 pf[2]; \
      _Pragma("unroll") \
      for (int mb = 0; mb < 2; ++mb) \
        pf[mb] = *(const bf16x8*)&p_s[(wave * 32 + mb * 16 + lr) * 64 + pc]; \
      _Pragma("unroll") \
      for (int db = 0; db < 8; ++db) { \
        bf16x8 vf = *(const bf16x8*)&vT_s[BUF][(db * 16 + lr) * 64 + pc]; \
        _Pragma("unroll") \
        for (int mb = 0; mb < 2; ++mb) \
          o_acc[mb][db] = MFMA16(pf[mb], vf, o_acc[mb][db]); \
      } \
    } \
    __builtin_amdgcn_s_setprio(0); \
    if ((JT) >= 30) { asm volatile("s_waitcnt vmcnt(0)" ::: "memory"); } \
    else            { asm volatile("s_waitcnt vmcnt(2)" ::: "memory"); } \
    __builtin_amdgcn_s_barrier();        /* b2: K/V(JT+1) landed; K(JT+2) in flight */ \
    __builtin_amdgcn_sched_barrier(0); \
    if ((JT) <= 29) ISSUE_V((JT) + 2, BUF); \
  } while (0)

#pragma unroll 1
  for (int jtb = 0; jtb < 16; ++jtb) {
    const int jt0 = jtb * 2;
    STEP(jt0, 0);
    STEP(jt0 + 1, 1);
  }
#undef STEP
#undef ISSUE_K
#undef ISSUE_V

  // ================= fused output projection epilogue =================
  // stage Wout fp32 -> bf16 into wout_s (512 threads cover 128x128)
#pragma unroll
  for (int p = 0; p < 4; ++p) {
    int r = p * 32 + (tid >> 4);
    int c = (tid & 15) * 8;
    float4 v0 = *(const float4*)(Wout + (size_t)r * 128 + c);
    float4 v1 = *(const float4*)(Wout + (size_t)r * 128 + c + 4);
    u16x4 pk0, pk1;
    pk0.x = f2bf(v0.x); pk0.y = f2bf(v0.y); pk0.z = f2bf(v0.z); pk0.w = f2bf(v0.w);
    pk1.x = f2bf(v1.x); pk1.y = f2bf(v1.y); pk1.z = f2bf(v1.z); pk1.w = f2bf(v1.w);
    *(u16x4*)&wout_s[r * 136 + c] = pk0;
    *(u16x4*)&wout_s[r * 136 + c + 4] = pk1;
  }

  // l into C-layout (wave-local roundtrip), fold 1/l into o_acc
#pragma unroll
  for (int mb = 0; mb < 2; ++mb)
    if (lane < 16) redu_s[wave][mb][lane] = l_i[mb];
#pragma unroll
  for (int mb = 0; mb < 2; ++mb) {
    f32x4 l4 = *(const f32x4*)&redu_s[wave][mb][quad * 4];
    f32x4 invv;
#pragma unroll
    for (int r = 0; r < 4; ++r) invv[r] = 1.f / l4[r];
#pragma unroll
    for (int db = 0; db < 8; ++db) o_acc[mb][db] *= invv;
  }

  __syncthreads();   // wout_s staged (also: all waves past main loop)

  f32x4 acc2[2][8];
#pragma unroll
  for (int mb = 0; mb < 2; ++mb)
#pragma unroll
    for (int nb = 0; nb < 8; ++nb) acc2[mb][nb] = zero;

  // two k-halves through the wave-private p_s region (rows wave*32..+32)
#pragma unroll
  for (int h = 0; h < 2; ++h) {
    // write normalized O[:, h*64 .. h*64+64) as bf16 into p_s, XOR-swizzled
#pragma unroll
    for (int mb = 0; mb < 2; ++mb)
#pragma unroll
      for (int db2 = 0; db2 < 4; ++db2) {
        f32x4 o = o_acc[mb][h * 4 + db2];
#pragma unroll
        for (int r = 0; r < 4; ++r) {
          int row = mb * 16 + quad * 4 + r;     // within wave's 32 rows
          int colh = db2 * 16 + lr;             // 0..63 within half
          int chunk = colh >> 3, off = colh & 7;
          p_s[(wave * 32 + row) * 64 + ((chunk ^ (row & 7)) << 3) + off] = f2bf(o[r]);
        }
      }
    // wave-private: compiler inserts lgkmcnt before dependent reads
#pragma unroll
    for (int ks = 0; ks < 2; ++ks) {
#pragma unroll
      for (int mb = 0; mb < 2; ++mb) {
        int arow = mb * 16 + lr;
        int kk = ks * 32 + quad * 8;            // 0..63 within half
        int chunk = kk >> 3;                    // 16B-aligned
        bf16x8 af = *(const bf16x8*)&p_s[(wave * 32 + arow) * 64 + ((chunk ^ (arow & 7)) << 3)];
#pragma unroll
        for (int nb = 0; nb < 8; ++nb) {
          bf16x8 bf = *(const bf16x8*)&wout_s[(nb * 16 + lr) * 136 + h * 64 + kk];
          acc2[mb][nb] = MFMA16(af, bf, acc2[mb][nb]);
        }
      }
    }
  }

  // store fp32 output + bias
#pragma unroll
  for (int mb = 0; mb < 2; ++mb)
#pragma unroll
    for (int nb = 0; nb < 8; ++nb) {
      int col = nb * 16 + lr;
      float b = bias[col];
#pragma unroll
      for (int r = 0; r < 4; ++r) {
        int row = wave * 32 + mb * 16 + quad * 4 + r;
        OUT[(size_t)row * 128 + col] = acc2[mb][nb][r] + b;
      }
    }
}

extern "C" void kernel_launch(void* const* d_in, const int* in_sizes, int n_in,
                              void* d_out, int out_size, void* d_ws, size_t ws_size,
                              hipStream_t stream) {
  const float* q    = (const float*)d_in[0];
  const float* kv   = (const float*)d_in[1];
  const float* Wq   = (const float*)d_in[2];
  const float* Wkv  = (const float*)d_in[3];
  const float* Wout = (const float*)d_in[4];
  const float* bout = (const float*)d_in[5];
  float* out = (float*)d_out;

  const size_t NELEM = (size_t)131072 * 128;
  unsigned short* qp_b = (unsigned short*)d_ws;
  unsigned short* k_b  = qp_b + NELEM;
  unsigned short* vT_b = k_b + NELEM;   // [bh][128][2048]

  // 128^-0.5 * log2(e): softmax computed in exp2 domain
  const float SCALE2 = 0.08838834764831845f * 1.4426950408889634f;

  conv_w<<<dim3(48), 256, 0, stream>>>(Wq, Wkv);
  proj_qkv<<<dim3(4096), 256, 0, stream>>>(q, kv, qp_b, k_b, vT_b, SCALE2);
  attn_fused<<<dim3(512), 512, 0, stream>>>(qp_b, k_b, vT_b, Wout, bout, out);
}